// Round 4
// baseline (338.267 us; speedup 1.0000x reference)
//
#include <hip/hip_runtime.h>
#include <hip/hip_bf16.h>
#include <math.h>

#define TT   1024
#define HH   1024
#define II   512
#define EE   32
#define NE   40
#define TOPK 4
#define CAP  1024

#define GM  128   // m-tile (slots) per block pass
#define GK  32    // k-slab per pipeline step

typedef __attribute__((ext_vector_type(4))) short short4v;
typedef __attribute__((ext_vector_type(8))) short short8v;
typedef __attribute__((ext_vector_type(4))) float floatx4;

static __device__ __forceinline__ short f2bf(float f) {
    unsigned u = __float_as_uint(f);
    unsigned r = (u + 0x7fffu + ((u >> 16) & 1u)) >> 16;
    return (short)(r & 0xffffu);
}
static __device__ __forceinline__ float bf2f(short s) {
    return __uint_as_float(((unsigned)(unsigned short)s) << 16);
}
#if defined(__has_builtin)
#if __has_builtin(__builtin_amdgcn_cvt_pk_bf16_f32)
#define HAVE_PK_BF16 1
#endif
#endif
static __device__ __forceinline__ unsigned pk2(float a, float b) {
#ifdef HAVE_PK_BF16
    typedef __attribute__((ext_vector_type(2))) __bf16 bf2t;
    union { bf2t v; unsigned u; } cv;
    cv.v = __builtin_amdgcn_cvt_pk_bf16_f32(a, b);
    return cv.u;
#else
    return (unsigned)(unsigned short)f2bf(a) | ((unsigned)(unsigned short)f2bf(b) << 16);
#endif
}
static __device__ __forceinline__ short4v cvt4(float4 v) {
    union { unsigned u[2]; short4v s; } cv;
    cv.u[0] = pk2(v.x, v.y); cv.u[1] = pk2(v.z, v.w);
    return cv.s;
}
// pack 8 consecutive fp32 (two float4) into a bf16 MFMA fragment register
static __device__ __forceinline__ short8v pack8(float4 f0, float4 f1) {
    union { short4v h[2]; short8v v; } u;
    u.h[0] = cvt4(f0); u.h[1] = cvt4(f1);
    return u.v;
}

// ---------------- workspace layout (bytes) ----------------
// counts @0, topk_w @1024, zero_w @17408, kexp @21504, slots @40960,
// xb @262144 (2MB), hmid @2359296 (4MB), ydown @6553600 (8MB)

// ================= Phase A: router (waves 0,1) + xconv (waves 2,3) ============
__global__ __launch_bounds__(256, 4) void kA(
    const float* __restrict__ x, const float* __restrict__ rw,
    const float* __restrict__ bias, float* __restrict__ topk_w,
    float* __restrict__ zero_w, int* __restrict__ kexp,
    int* __restrict__ counts, int* __restrict__ slots, short* __restrict__ xb)
{
    const int bx = blockIdx.x, tid = threadIdx.x;
    const int lane = tid & 63;
    const int w    = tid >> 6;

    if (w < 2) {
        const int t = bx * 2 + w;
        float xv[16];
        #pragma unroll
        for (int i = 0; i < 16; ++i) xv[i] = x[(size_t)t * HH + 64 * i + lane];

        float mylogit = -INFINITY;
        for (int e0 = 0; e0 < NE; e0 += 4) {
            const float* r0 = rw + (size_t)e0 * HH;
            float p[4] = { 0.f, 0.f, 0.f, 0.f };
            #pragma unroll
            for (int i = 0; i < 16; ++i) {
                int h = 64 * i + lane;
                #pragma unroll
                for (int j = 0; j < 4; ++j) p[j] += xv[i] * r0[(size_t)j * HH + h];
            }
            #pragma unroll
            for (int j = 0; j < 4; ++j) {
                #pragma unroll
                for (int off = 32; off > 0; off >>= 1) p[j] += __shfl_xor(p[j], off);
                if (lane == e0 + j) mylogit = p[j];
            }
        }

        float m = mylogit;
        #pragma unroll
        for (int off = 32; off > 0; off >>= 1) m = fmaxf(m, __shfl_xor(m, off));
        float pexp = (lane < NE) ? expf(mylogit - m) : 0.f;
        float s = pexp;
        #pragma unroll
        for (int off = 32; off > 0; off >>= 1) s += __shfl_xor(s, off);
        const float score = pexp / s;

        float val = (lane < NE) ? score + bias[lane] : -INFINITY;
        int   kidx[TOPK];
        float kw[TOPK];
        #pragma unroll
        for (int k = 0; k < TOPK; ++k) {
            float v = val; int idx = lane;
            #pragma unroll
            for (int off = 32; off > 0; off >>= 1) {
                float ov = __shfl_xor(v, off);
                int   oi = __shfl_xor(idx, off);
                if (ov > v || (ov == v && oi < idx)) { v = ov; idx = oi; }
            }
            kidx[k] = idx;
            kw[k]   = __shfl(score, idx);
            if (lane == idx) val = -INFINITY;
        }

        if (lane == 0) {
            float zw = 0.f;
            #pragma unroll
            for (int k = 0; k < TOPK; ++k) {
                int slot = t * TOPK + k;
                topk_w[slot] = kw[k];
                kexp[slot]   = kidx[k];
                if (kidx[k] < EE) {
                    int pos = atomicAdd(&counts[kidx[k]], 1);
                    slots[kidx[k] * CAP + pos] = slot;
                } else {
                    zw += kw[k];
                }
            }
            zero_w[t] = zw;
        }
    } else {
        const int t = bx * 2 + (w - 2);
        const float4* xr = (const float4*)(x + (size_t)t * HH);
        short4v* xbr = (short4v*)(xb + (size_t)t * HH);
        #pragma unroll
        for (int i = 0; i < 4; ++i) xbr[lane + 64 * i] = cvt4(xr[lane + 64 * i]);
    }
}

// ================= Phase B: gate_up bf16 MFMA + SiLU ==========================
// grid 512 = E(32) x 16 column tiles (32 hmid cols each).
// Waves: 2(m-half: 64 slots) x 2(n-half: 16 cols). NO k-loop LDS, NO barriers:
// A fragments (xb, bf16) and B fragments (wgu, fp32->bf16 in-reg) are loaded
// directly from global in MFMA fragment layout.
__global__ __launch_bounds__(256, 2) void kB(
    const short* __restrict__ xb, const float* __restrict__ wgu,
    const int* __restrict__ counts, const int* __restrict__ slots,
    const float* __restrict__ topk_w, short* __restrict__ hmid)
{
    __shared__ int   ssl[GM];
    __shared__ float swv[GM];
    const int bx = blockIdx.x, tid = threadIdx.x;
    const int e      = bx >> 4;
    const int c_base = (bx & 15) * 32;
    const int cnt    = counts[e];
    const float* wb  = wgu + (size_t)e * (2 * II) * HH;

    const int lane = tid & 63;
    const int w    = tid >> 6;
    const int wm   = w >> 1;          // 0..1 : m-half (64 slots)
    const int wn   = w & 1;           // 0..1 : n-half (16 cols)
    const int quad = lane >> 4;
    const int mcol = lane & 15;
    constexpr int NT = HH / GK;       // 32 (even)

    // B row pointers: gate row and up row for this lane (fragment layout:
    // lane holds W[n = base+mcol][k = quad*8 .. +7], 8 contiguous fp32).
    const float* pG = wb + (size_t)(c_base + wn * 16 + mcol) * HH + quad * 8;
    const float* pU = wb + (size_t)(II + c_base + wn * 16 + mcol) * HH + quad * 8;

    for (int m_base = 0; m_base < cnt; m_base += GM) {
        __syncthreads();   // protect ssl/swv reuse across m-passes
        if (tid < GM) {
            int m = m_base + tid;
            int s = (m < cnt) ? slots[e * CAP + m] : -1;
            ssl[tid] = s;
            swv[tid] = (s >= 0) ? topk_w[s] : 0.f;
        }
        __syncthreads();

        // A row pointers (4 fragments x 16 rows): lane holds
        // xb[tokrow(m = wm*64 + i*16 + mcol)][k = quad*8 .. +7] (16B contiguous).
        const short* pA0, *pA1, *pA2, *pA3;
        {
            int s0 = ssl[wm * 64 +  0 + mcol];
            int s1 = ssl[wm * 64 + 16 + mcol];
            int s2 = ssl[wm * 64 + 32 + mcol];
            int s3 = ssl[wm * 64 + 48 + mcol];
            pA0 = xb + (size_t)(((s0 >= 0 ? s0 : 0)) >> 2) * HH + quad * 8;
            pA1 = xb + (size_t)(((s1 >= 0 ? s1 : 0)) >> 2) * HH + quad * 8;
            pA2 = xb + (size_t)(((s2 >= 0 ? s2 : 0)) >> 2) * HH + quad * 8;
            pA3 = xb + (size_t)(((s3 >= 0 ? s3 : 0)) >> 2) * HH + quad * 8;
        }

        floatx4 accg[4] = {};
        floatx4 accu[4] = {};
        short8v aA0, aA1, aA2, aA3, aB0, aB1, aB2, aB3;
        float4  gA0, gA1, uA0, uA1, gB0, gB1, uB0, uB1;

        // prologue: slab 0 -> set A
        aA0 = *(const short8v*)(pA0);
        aA1 = *(const short8v*)(pA1);
        aA2 = *(const short8v*)(pA2);
        aA3 = *(const short8v*)(pA3);
        gA0 = *(const float4*)(pG);     gA1 = *(const float4*)(pG + 4);
        uA0 = *(const float4*)(pU);     uA1 = *(const float4*)(pU + 4);

        for (int t = 0; t < NT; t += 2) {
            const int k1 = (t + 1) * GK;   // always < HH inside loop
            // issue slab k1 -> set B
            aB0 = *(const short8v*)(pA0 + k1);
            aB1 = *(const short8v*)(pA1 + k1);
            aB2 = *(const short8v*)(pA2 + k1);
            aB3 = *(const short8v*)(pA3 + k1);
            gB0 = *(const float4*)(pG + k1); gB1 = *(const float4*)(pG + k1 + 4);
            uB0 = *(const float4*)(pU + k1); uB1 = *(const float4*)(pU + k1 + 4);
            // compute set A (slab t*GK)
            {
                short8v bg = pack8(gA0, gA1), bu = pack8(uA0, uA1);
                accg[0] = __builtin_amdgcn_mfma_f32_16x16x32_bf16(aA0, bg, accg[0], 0, 0, 0);
                accu[0] = __builtin_amdgcn_mfma_f32_16x16x32_bf16(aA0, bu, accu[0], 0, 0, 0);
                accg[1] = __builtin_amdgcn_mfma_f32_16x16x32_bf16(aA1, bg, accg[1], 0, 0, 0);
                accu[1] = __builtin_amdgcn_mfma_f32_16x16x32_bf16(aA1, bu, accu[1], 0, 0, 0);
                accg[2] = __builtin_amdgcn_mfma_f32_16x16x32_bf16(aA2, bg, accg[2], 0, 0, 0);
                accu[2] = __builtin_amdgcn_mfma_f32_16x16x32_bf16(aA2, bu, accu[2], 0, 0, 0);
                accg[3] = __builtin_amdgcn_mfma_f32_16x16x32_bf16(aA3, bg, accg[3], 0, 0, 0);
                accu[3] = __builtin_amdgcn_mfma_f32_16x16x32_bf16(aA3, bu, accu[3], 0, 0, 0);
            }
            const int k2 = (t + 2) * GK;
            if (k2 < HH) {   // issue slab k2 -> set A
                aA0 = *(const short8v*)(pA0 + k2);
                aA1 = *(const short8v*)(pA1 + k2);
                aA2 = *(const short8v*)(pA2 + k2);
                aA3 = *(const short8v*)(pA3 + k2);
                gA0 = *(const float4*)(pG + k2); gA1 = *(const float4*)(pG + k2 + 4);
                uA0 = *(const float4*)(pU + k2); uA1 = *(const float4*)(pU + k2 + 4);
            }
            // compute set B (slab k1)
            {
                short8v bg = pack8(gB0, gB1), bu = pack8(uB0, uB1);
                accg[0] = __builtin_amdgcn_mfma_f32_16x16x32_bf16(aB0, bg, accg[0], 0, 0, 0);
                accu[0] = __builtin_amdgcn_mfma_f32_16x16x32_bf16(aB0, bu, accu[0], 0, 0, 0);
                accg[1] = __builtin_amdgcn_mfma_f32_16x16x32_bf16(aB1, bg, accg[1], 0, 0, 0);
                accu[1] = __builtin_amdgcn_mfma_f32_16x16x32_bf16(aB1, bu, accu[1], 0, 0, 0);
                accg[2] = __builtin_amdgcn_mfma_f32_16x16x32_bf16(aB2, bg, accg[2], 0, 0, 0);
                accu[2] = __builtin_amdgcn_mfma_f32_16x16x32_bf16(aB2, bu, accu[2], 0, 0, 0);
                accg[3] = __builtin_amdgcn_mfma_f32_16x16x32_bf16(aB3, bg, accg[3], 0, 0, 0);
                accu[3] = __builtin_amdgcn_mfma_f32_16x16x32_bf16(aB3, bu, accu[3], 0, 0, 0);
            }
        }

        #pragma unroll
        for (int i = 0; i < 4; ++i) {
            #pragma unroll
            for (int r = 0; r < 4; ++r) {
                int m = wm * 64 + i * 16 + quad * 4 + r;
                int s = ssl[m];
                if (s < 0) continue;
                float g = accg[i][r], u = accu[i][r];
                float valf = swv[m] * g * u / (1.f + __expf(-g));
                hmid[(size_t)s * II + c_base + wn * 16 + mcol] = f2bf(valf);
            }
        }
    }
}

// ================= Phase C: down bf16 MFMA -> ydown ===========================
// grid 512 = E(32) x 16 h-tiles (64 cols each). Waves 2(m)x2(n: 32 cols).
// Same direct-from-global fragment scheme; k = II, 16 slabs.
__global__ __launch_bounds__(256, 2) void kC(
    const short* __restrict__ hmid, const float* __restrict__ wd,
    const int* __restrict__ counts, const int* __restrict__ slots,
    short* __restrict__ ydown)
{
    __shared__ int ssl[GM];
    const int bx = blockIdx.x, tid = threadIdx.x;
    const int e      = bx >> 4;
    const int n_base = (bx & 15) * 64;
    const int cnt    = counts[e];
    const float* wb  = wd + (size_t)e * HH * II;

    const int lane = tid & 63;
    const int w    = tid >> 6;
    const int wm   = w >> 1;          // 0..1 : m-half (64 slots)
    const int wn   = w & 1;           // 0..1 : n-half (32 cols)
    const int quad = lane >> 4;
    const int mcol = lane & 15;
    constexpr int NT = II / GK;       // 16 (even)

    // B row pointers: two 16-col fragments
    const float* pW0 = wb + (size_t)(n_base + wn * 32 +      mcol) * II + quad * 8;
    const float* pW1 = wb + (size_t)(n_base + wn * 32 + 16 + mcol) * II + quad * 8;

    for (int m_base = 0; m_base < cnt; m_base += GM) {
        __syncthreads();
        if (tid < GM) {
            int m = m_base + tid;
            ssl[tid] = (m < cnt) ? slots[e * CAP + m] : -1;
        }
        __syncthreads();

        const short* pA0, *pA1, *pA2, *pA3;
        {
            int s0 = ssl[wm * 64 +  0 + mcol];
            int s1 = ssl[wm * 64 + 16 + mcol];
            int s2 = ssl[wm * 64 + 32 + mcol];
            int s3 = ssl[wm * 64 + 48 + mcol];
            pA0 = hmid + (size_t)(s0 >= 0 ? s0 : 0) * II + quad * 8;
            pA1 = hmid + (size_t)(s1 >= 0 ? s1 : 0) * II + quad * 8;
            pA2 = hmid + (size_t)(s2 >= 0 ? s2 : 0) * II + quad * 8;
            pA3 = hmid + (size_t)(s3 >= 0 ? s3 : 0) * II + quad * 8;
        }

        floatx4 acc0[4] = {};   // n-frag 0
        floatx4 acc1[4] = {};   // n-frag 1
        short8v aA0, aA1, aA2, aA3, aB0, aB1, aB2, aB3;
        float4  w0A0, w0A1, w1A0, w1A1, w0B0, w0B1, w1B0, w1B1;

        aA0 = *(const short8v*)(pA0);
        aA1 = *(const short8v*)(pA1);
        aA2 = *(const short8v*)(pA2);
        aA3 = *(const short8v*)(pA3);
        w0A0 = *(const float4*)(pW0);     w0A1 = *(const float4*)(pW0 + 4);
        w1A0 = *(const float4*)(pW1);     w1A1 = *(const float4*)(pW1 + 4);

        for (int t = 0; t < NT; t += 2) {
            const int k1 = (t + 1) * GK;
            aB0 = *(const short8v*)(pA0 + k1);
            aB1 = *(const short8v*)(pA1 + k1);
            aB2 = *(const short8v*)(pA2 + k1);
            aB3 = *(const short8v*)(pA3 + k1);
            w0B0 = *(const float4*)(pW0 + k1); w0B1 = *(const float4*)(pW0 + k1 + 4);
            w1B0 = *(const float4*)(pW1 + k1); w1B1 = *(const float4*)(pW1 + k1 + 4);
            {
                short8v b0 = pack8(w0A0, w0A1), b1 = pack8(w1A0, w1A1);
                acc0[0] = __builtin_amdgcn_mfma_f32_16x16x32_bf16(aA0, b0, acc0[0], 0, 0, 0);
                acc1[0] = __builtin_amdgcn_mfma_f32_16x16x32_bf16(aA0, b1, acc1[0], 0, 0, 0);
                acc0[1] = __builtin_amdgcn_mfma_f32_16x16x32_bf16(aA1, b0, acc0[1], 0, 0, 0);
                acc1[1] = __builtin_amdgcn_mfma_f32_16x16x32_bf16(aA1, b1, acc1[1], 0, 0, 0);
                acc0[2] = __builtin_amdgcn_mfma_f32_16x16x32_bf16(aA2, b0, acc0[2], 0, 0, 0);
                acc1[2] = __builtin_amdgcn_mfma_f32_16x16x32_bf16(aA2, b1, acc1[2], 0, 0, 0);
                acc0[3] = __builtin_amdgcn_mfma_f32_16x16x32_bf16(aA3, b0, acc0[3], 0, 0, 0);
                acc1[3] = __builtin_amdgcn_mfma_f32_16x16x32_bf16(aA3, b1, acc1[3], 0, 0, 0);
            }
            const int k2 = (t + 2) * GK;
            if (k2 < II) {
                aA0 = *(const short8v*)(pA0 + k2);
                aA1 = *(const short8v*)(pA1 + k2);
                aA2 = *(const short8v*)(pA2 + k2);
                aA3 = *(const short8v*)(pA3 + k2);
                w0A0 = *(const float4*)(pW0 + k2); w0A1 = *(const float4*)(pW0 + k2 + 4);
                w1A0 = *(const float4*)(pW1 + k2); w1A1 = *(const float4*)(pW1 + k2 + 4);
            }
            {
                short8v b0 = pack8(w0B0, w0B1), b1 = pack8(w1B0, w1B1);
                acc0[0] = __builtin_amdgcn_mfma_f32_16x16x32_bf16(aB0, b0, acc0[0], 0, 0, 0);
                acc1[0] = __builtin_amdgcn_mfma_f32_16x16x32_bf16(aB0, b1, acc1[0], 0, 0, 0);
                acc0[1] = __builtin_amdgcn_mfma_f32_16x16x32_bf16(aB1, b0, acc0[1], 0, 0, 0);
                acc1[1] = __builtin_amdgcn_mfma_f32_16x16x32_bf16(aB1, b1, acc1[1], 0, 0, 0);
                acc0[2] = __builtin_amdgcn_mfma_f32_16x16x32_bf16(aB2, b0, acc0[2], 0, 0, 0);
                acc1[2] = __builtin_amdgcn_mfma_f32_16x16x32_bf16(aB2, b1, acc1[2], 0, 0, 0);
                acc0[3] = __builtin_amdgcn_mfma_f32_16x16x32_bf16(aB3, b0, acc0[3], 0, 0, 0);
                acc1[3] = __builtin_amdgcn_mfma_f32_16x16x32_bf16(aB3, b1, acc1[3], 0, 0, 0);
            }
        }

        #pragma unroll
        for (int i = 0; i < 4; ++i) {
            #pragma unroll
            for (int r = 0; r < 4; ++r) {
                int m = wm * 64 + i * 16 + quad * 4 + r;
                int s = ssl[m];
                if (s < 0) continue;
                short* yrow = ydown + (size_t)s * HH + n_base + wn * 32;
                yrow[mcol]      = f2bf(acc0[i][r]);
                yrow[16 + mcol] = f2bf(acc1[i][r]);
            }
        }
    }
}

// ================= Phase D: combine (grid 1024, 1 token/block) ================
__global__ __launch_bounds__(256, 4) void kD(
    const float* __restrict__ x, const short* __restrict__ ydown,
    const int* __restrict__ kexp, const float* __restrict__ zero_w,
    float* __restrict__ out)
{
    const int bx = blockIdx.x, tid = threadIdx.x;
    const int t = bx;
    const float4 xvv = ((const float4*)(x + (size_t)t * HH))[tid];
    const float zw = zero_w[t];
    float4 o;
    o.x = zw * xvv.x; o.y = zw * xvv.y; o.z = zw * xvv.z; o.w = zw * xvv.w;
    #pragma unroll
    for (int k = 0; k < TOPK; ++k) {
        int slot = t * TOPK + k;
        if (kexp[slot] < EE) {
            short4v y = *(const short4v*)&ydown[(size_t)slot * HH + tid * 4];
            o.x += bf2f(y[0]); o.y += bf2f(y[1]);
            o.z += bf2f(y[2]); o.w += bf2f(y[3]);
        }
    }
    ((float4*)(out + (size_t)t * HH))[tid] = o;
}

extern "C" void kernel_launch(void* const* d_in, const int* in_sizes, int n_in,
                              void* d_out, int out_size, void* d_ws, size_t ws_size,
                              hipStream_t stream) {
    const float* x    = (const float*)d_in[0];
    const float* rw   = (const float*)d_in[1];
    const float* bias = (const float*)d_in[2];
    const float* wgu  = (const float*)d_in[3];
    const float* wd   = (const float*)d_in[4];
    float* out = (float*)d_out;

    char* ws = (char*)d_ws;
    int*   counts = (int*)ws;
    float* topk_w = (float*)(ws + 1024);
    float* zero_w = (float*)(ws + 17408);
    int*   kexp   = (int*)(ws + 21504);
    int*   slots  = (int*)(ws + 40960);
    short* xb     = (short*)(ws + 262144);
    short* hmid   = (short*)(ws + 2359296);
    short* ydown  = (short*)(ws + 6553600);

    hipMemsetAsync(counts, 0, EE * sizeof(int), stream);

    kA<<<dim3(512), dim3(256), 0, stream>>>(x, rw, bias, topk_w, zero_w, kexp, counts, slots, xb);
    kB<<<dim3(512), dim3(256), 0, stream>>>(xb, wgu, counts, slots, topk_w, hmid);
    kC<<<dim3(512), dim3(256), 0, stream>>>(hmid, wd, counts, slots, ydown);
    kD<<<dim3(1024), dim3(256), 0, stream>>>(x, ydown, kexp, zero_w, out);
}